// Round 2
// baseline (745.163 us; speedup 1.0000x reference)
//
#include <hip/hip_runtime.h>
#include <hip/hip_bf16.h>

// MoE router+dispatch+combine, split into 3 kernels for occupancy:
//   prep:    rw fp32 -> bf16 hi/lo (ws)                 [tiny]
//   router:  logits via bf16x3 MFMA, softmax, top-8 -> ws
//   combine: out[t] = flat[t]*wsum + sum_k w_k*eb[idx_k]  (streaming)
// T=16384, H=4096, E=64, K=8, fp32 in/out.

typedef float f32x4 __attribute__((ext_vector_type(4)));
typedef short s16x8 __attribute__((ext_vector_type(8)));   // 8 bf16 (4 VGPRs)

#define HH 4096
#define EE 64
#define KTOP 8

// ---- ws layout (bytes) ----
#define WS_WHI 0u
#define WS_WLO (EE * HH * 2u)                  // 524288
#define WS_TW  (WS_WLO + EE * HH * 2u)         // 1048576
#define WS_TSUM(T) (WS_TW + (unsigned)(T) * 8u * 4u)
#define WS_TIDX(T) (WS_TSUM(T) + (unsigned)(T) * 4u)
#define WS_REQ(T)  (WS_TIDX(T) + (unsigned)(T) * 8u * 4u)

__device__ __forceinline__ short f2bf(float x) {
  __hip_bfloat16 h = __float2bfloat16(x);      // RNE
  return *reinterpret_cast<const short*>(&h);
}
__device__ __forceinline__ float bf2f(short s) {
  union { unsigned u; float f; } v;
  v.u = ((unsigned)(unsigned short)s) << 16;
  return v.f;
}

// Split 8 fp32 into bf16 hi + bf16 lo fragments (fp32 ~= hi + lo).
__device__ __forceinline__ void split8(const float4& a, const float4& b,
                                       s16x8& hi, s16x8& lo) {
  float x[8] = {a.x, a.y, a.z, a.w, b.x, b.y, b.z, b.w};
#pragma unroll
  for (int i = 0; i < 8; ++i) {
    short hb = f2bf(x[i]);
    float hf = bf2f(hb);
    short lb = f2bf(x[i] - hf);
    hi[i] = hb;
    lo[i] = lb;
  }
}

// ---------------- kernel 0: pre-split router weights ------------------------
__global__ __launch_bounds__(256) void prep_split(const float* __restrict__ rw,
                                                  short* __restrict__ whi,
                                                  short* __restrict__ wlo) {
  const int i = blockIdx.x * blockDim.x + threadIdx.x;   // group of 8 floats
  const float4 a = reinterpret_cast<const float4*>(rw)[2 * i];
  const float4 b = reinterpret_cast<const float4*>(rw)[2 * i + 1];
  s16x8 hi, lo;
  split8(a, b, hi, lo);
  *reinterpret_cast<s16x8*>(whi + 8 * (size_t)i) = hi;
  *reinterpret_cast<s16x8*>(wlo + 8 * (size_t)i) = lo;
}

// ---------------- kernel 1: router (logits + softmax + top-8) ---------------
// 16 tokens/block, 4 waves k-split 4x1024. 1024 blocks -> 16 waves/CU.
__global__ __launch_bounds__(256, 4) void router_topk(
    const float* __restrict__ flat, const short* __restrict__ whi,
    const short* __restrict__ wlo, const float* __restrict__ rb,
    float* __restrict__ tw, float* __restrict__ tsum, int* __restrict__ tidx) {
  __shared__ float lg[4][16][EE + 2];

  const int tid  = threadIdx.x;
  const int lane = tid & 63;
  const int wv   = tid >> 6;
  const int lrow = lane & 15;
  const int lkg  = lane >> 4;
  const size_t t0 = (size_t)blockIdx.x * 16;

  f32x4 acc[4];
#pragma unroll
  for (int e = 0; e < 4; ++e) acc[e] = (f32x4){0.f, 0.f, 0.f, 0.f};

  const int kb = wv * (HH / 4) + lkg * 8;
  const float* pA = flat + (t0 + lrow) * HH + kb;
  const short* pH = whi + (size_t)lrow * HH + kb;
  const short* pL = wlo + (size_t)lrow * HH + kb;

  float4 a0, a1; s16x8 wh0, wh1, wh2, wh3, wl0, wl1, wl2, wl3;
  a0 = *(const float4*)(pA);
  a1 = *(const float4*)(pA + 4);
  wh0 = *(const s16x8*)(pH + 0 * 16 * HH); wl0 = *(const s16x8*)(pL + 0 * 16 * HH);
  wh1 = *(const s16x8*)(pH + 1 * 16 * HH); wl1 = *(const s16x8*)(pL + 1 * 16 * HH);
  wh2 = *(const s16x8*)(pH + 2 * 16 * HH); wl2 = *(const s16x8*)(pL + 2 * 16 * HH);
  wh3 = *(const s16x8*)(pH + 3 * 16 * HH); wl3 = *(const s16x8*)(pL + 3 * 16 * HH);

  for (int s = 0; s < 32; ++s) {
    s16x8 Ah, Al;
    split8(a0, a1, Ah, Al);
    s16x8 ch0 = wh0, ch1 = wh1, ch2 = wh2, ch3 = wh3;
    s16x8 cl0 = wl0, cl1 = wl1, cl2 = wl2, cl3 = wl3;

    if (s + 1 < 32) {                        // prefetch next step
      const int ko = (s + 1) * 32;
      a0 = *(const float4*)(pA + ko);
      a1 = *(const float4*)(pA + ko + 4);
      wh0 = *(const s16x8*)(pH + 0 * 16 * HH + ko); wl0 = *(const s16x8*)(pL + 0 * 16 * HH + ko);
      wh1 = *(const s16x8*)(pH + 1 * 16 * HH + ko); wl1 = *(const s16x8*)(pL + 1 * 16 * HH + ko);
      wh2 = *(const s16x8*)(pH + 2 * 16 * HH + ko); wl2 = *(const s16x8*)(pL + 2 * 16 * HH + ko);
      wh3 = *(const s16x8*)(pH + 3 * 16 * HH + ko); wl3 = *(const s16x8*)(pL + 3 * 16 * HH + ko);
    }

    // 3-pass fp32 emulation: hh + hl + lh
    acc[0] = __builtin_amdgcn_mfma_f32_16x16x32_bf16(Ah, ch0, acc[0], 0, 0, 0);
    acc[0] = __builtin_amdgcn_mfma_f32_16x16x32_bf16(Ah, cl0, acc[0], 0, 0, 0);
    acc[0] = __builtin_amdgcn_mfma_f32_16x16x32_bf16(Al, ch0, acc[0], 0, 0, 0);
    acc[1] = __builtin_amdgcn_mfma_f32_16x16x32_bf16(Ah, ch1, acc[1], 0, 0, 0);
    acc[1] = __builtin_amdgcn_mfma_f32_16x16x32_bf16(Ah, cl1, acc[1], 0, 0, 0);
    acc[1] = __builtin_amdgcn_mfma_f32_16x16x32_bf16(Al, ch1, acc[1], 0, 0, 0);
    acc[2] = __builtin_amdgcn_mfma_f32_16x16x32_bf16(Ah, ch2, acc[2], 0, 0, 0);
    acc[2] = __builtin_amdgcn_mfma_f32_16x16x32_bf16(Ah, cl2, acc[2], 0, 0, 0);
    acc[2] = __builtin_amdgcn_mfma_f32_16x16x32_bf16(Al, ch2, acc[2], 0, 0, 0);
    acc[3] = __builtin_amdgcn_mfma_f32_16x16x32_bf16(Ah, ch3, acc[3], 0, 0, 0);
    acc[3] = __builtin_amdgcn_mfma_f32_16x16x32_bf16(Ah, cl3, acc[3], 0, 0, 0);
    acc[3] = __builtin_amdgcn_mfma_f32_16x16x32_bf16(Al, ch3, acc[3], 0, 0, 0);
  }

  // C/D: col(expert)=lane&15, row(token)=(lane>>4)*4+reg  [m89]
#pragma unroll
  for (int e = 0; e < 4; ++e)
#pragma unroll
    for (int r = 0; r < 4; ++r)
      lg[wv][(lane >> 4) * 4 + r][e * 16 + (lane & 15)] = acc[e][r];
  __syncthreads();

  // k-split reduce + bias
#pragma unroll
  for (int i = 0; i < (16 * EE) / 256; ++i) {   // 4 entries/thread
    int idx = tid + 256 * i;
    int t = idx >> 6, e = idx & 63;
    lg[0][t][e] = lg[0][t][e] + lg[1][t][e] + lg[2][t][e] + lg[3][t][e] + rb[e];
  }
  __syncthreads();

  // softmax + top-8, 4 tokens per wave
  for (int i = 0; i < 4; ++i) {
    const int tl = wv * 4 + i;
    const size_t tg = t0 + tl;
    float l = lg[0][tl][lane];               // lane = expert
    float m = l;
#pragma unroll
    for (int off = 32; off > 0; off >>= 1) m = fmaxf(m, __shfl_xor(m, off, 64));
    float p = __expf(l - m);
    float sum = p;
#pragma unroll
    for (int off = 32; off > 0; off >>= 1) sum += __shfl_xor(sum, off, 64);
    const float inv = 1.0f / sum;

    float cur = l;
    float wsum = 0.f;
    for (int k = 0; k < KTOP; ++k) {
      float v = cur;
      int a = lane;
#pragma unroll
      for (int off = 32; off > 0; off >>= 1) {
        float v2 = __shfl_xor(v, off, 64);
        int   a2 = __shfl_xor(a, off, 64);
        if (v2 > v || (v2 == v && a2 < a)) { v = v2; a = a2; }  // low idx wins ties
      }
      float wk = __shfl(p, a, 64) * inv;
      wsum += wk;
      if (lane == 0) { tw[tg * 8 + k] = wk; tidx[tg * 8 + k] = a; }
      if (lane == a) cur = -1e30f;
    }
    if (lane == 0) tsum[tg] = wsum;
  }
}

// ---------------- kernel 2: streaming combine -------------------------------
// 2048 blocks x 256 thr; each block 8 consecutive tokens.
__global__ __launch_bounds__(256, 4) void combine_stream(
    const float* __restrict__ flat, const float* __restrict__ eb,
    const float* __restrict__ tw, const float* __restrict__ tsum,
    const int* __restrict__ tidx, float* __restrict__ out) {
  const int tid = threadIdx.x;
  const int HV = HH / 4;
  for (int it = 0; it < 8; ++it) {
    const size_t t = (size_t)blockIdx.x * 8 + it;
    const float wsm = tsum[t];
    float wk[KTOP];
    const float4* ebp[KTOP];
#pragma unroll
    for (int k = 0; k < KTOP; ++k) {
      wk[k]  = tw[t * 8 + k];
      ebp[k] = reinterpret_cast<const float4*>(eb + (size_t)tidx[t * 8 + k] * HH);
    }
    const float4* fr   = reinterpret_cast<const float4*>(flat + t * HH);
    float4*       orow = reinterpret_cast<float4*>(out + t * HH);
#pragma unroll
    for (int i = 0; i < HV / 256; ++i) {     // 4 float4/thread
      const int h = tid + i * 256;
      float4 x = fr[h];
      float4 o;
      o.x = x.x * wsm; o.y = x.y * wsm; o.z = x.z * wsm; o.w = x.w * wsm;
#pragma unroll
      for (int k = 0; k < KTOP; ++k) {
        float4 b = ebp[k][h];
        o.x = fmaf(wk[k], b.x, o.x);
        o.y = fmaf(wk[k], b.y, o.y);
        o.z = fmaf(wk[k], b.z, o.z);
        o.w = fmaf(wk[k], b.w, o.w);
      }
      orow[h] = o;
    }
  }
}

// ---------------- fallback: R1 fused kernel (if ws too small) ---------------
#define TT 32
#define NT 256
__global__ __launch_bounds__(NT, 2) void moe_router_combine(
    const float* __restrict__ flat, const float* __restrict__ rw,
    const float* __restrict__ rb, const float* __restrict__ eb,
    float* __restrict__ out) {
  __shared__ float lgP[4][TT][EE + 2];
  __shared__ float twS[TT][KTOP + 1];
  __shared__ int   tiS[TT][KTOP];

  const int tid  = threadIdx.x;
  const int lane = tid & 63;
  const int wv   = tid >> 6;
  const int lrow = lane & 15;
  const int lkg  = lane >> 4;
  const size_t t0 = (size_t)blockIdx.x * TT;

  f32x4 acc[2][4];
#pragma unroll
  for (int m = 0; m < 2; ++m)
#pragma unroll
    for (int e = 0; e < 4; ++e) acc[m][e] = (f32x4){0.f, 0.f, 0.f, 0.f};

  const int kbase = wv * (HH / 4) + lkg * 8;
  const float* pA0 = flat + (t0 + lrow) * HH + kbase;
  const float* pA1 = flat + (t0 + 16 + lrow) * HH + kbase;
  const float* pW  = rw + (size_t)lrow * HH + kbase;

  float4 a00, a01, a10, a11, w0[4], w1[4];
  a00 = *(const float4*)(pA0); a01 = *(const float4*)(pA0 + 4);
  a10 = *(const float4*)(pA1); a11 = *(const float4*)(pA1 + 4);
#pragma unroll
  for (int et = 0; et < 4; ++et) {
    w0[et] = *(const float4*)(pW + (size_t)et * 16 * HH);
    w1[et] = *(const float4*)(pW + (size_t)et * 16 * HH + 4);
  }

  for (int s = 0; s < 32; ++s) {
    s16x8 Ah0, Al0, Ah1, Al1, Wh[4], Wl[4];
    split8(a00, a01, Ah0, Al0);
    split8(a10, a11, Ah1, Al1);
#pragma unroll
    for (int et = 0; et < 4; ++et) split8(w0[et], w1[et], Wh[et], Wl[et]);
    if (s + 1 < 32) {
      const int ko = (s + 1) * 32;
      a00 = *(const float4*)(pA0 + ko); a01 = *(const float4*)(pA0 + ko + 4);
      a10 = *(const float4*)(pA1 + ko); a11 = *(const float4*)(pA1 + ko + 4);
#pragma unroll
      for (int et = 0; et < 4; ++et) {
        w0[et] = *(const float4*)(pW + (size_t)et * 16 * HH + ko);
        w1[et] = *(const float4*)(pW + (size_t)et * 16 * HH + ko + 4);
      }
    }
#pragma unroll
    for (int et = 0; et < 4; ++et) {
      acc[0][et] = __builtin_amdgcn_mfma_f32_16x16x32_bf16(Ah0, Wh[et], acc[0][et], 0, 0, 0);
      acc[0][et] = __builtin_amdgcn_mfma_f32_16x16x32_bf16(Ah0, Wl[et], acc[0][et], 0, 0, 0);
      acc[0][et] = __builtin_amdgcn_mfma_f32_16x16x32_bf16(Al0, Wh[et], acc[0][et], 0, 0, 0);
      acc[1][et] = __builtin_amdgcn_mfma_f32_16x16x32_bf16(Ah1, Wh[et], acc[1][et], 0, 0, 0);
      acc[1][et] = __builtin_amdgcn_mfma_f32_16x16x32_bf16(Ah1, Wl[et], acc[1][et], 0, 0, 0);
      acc[1][et] = __builtin_amdgcn_mfma_f32_16x16x32_bf16(Al1, Wh[et], acc[1][et], 0, 0, 0);
    }
  }
#pragma unroll
  for (int mt = 0; mt < 2; ++mt)
#pragma unroll
    for (int et = 0; et < 4; ++et)
#pragma unroll
      for (int r = 0; r < 4; ++r)
        lgP[wv][mt * 16 + (lane >> 4) * 4 + r][et * 16 + (lane & 15)] = acc[mt][et][r];
  __syncthreads();
#pragma unroll
  for (int i = 0; i < (TT * EE) / NT; ++i) {
    int idx = tid + NT * i;
    int t = idx >> 6, e = idx & 63;
    lgP[0][t][e] = lgP[0][t][e] + lgP[1][t][e] + lgP[2][t][e] + lgP[3][t][e] + rb[e];
  }
  __syncthreads();
  for (int i = 0; i < TT / 4; ++i) {
    const int tl = wv * (TT / 4) + i;
    float l = lgP[0][tl][lane];
    float m = l;
#pragma unroll
    for (int off = 32; off > 0; off >>= 1) m = fmaxf(m, __shfl_xor(m, off, 64));
    float p = __expf(l - m);
    float sum = p;
#pragma unroll
    for (int off = 32; off > 0; off >>= 1) sum += __shfl_xor(sum, off, 64);
    const float inv = 1.0f / sum;
    float cur = l;
    float wsum = 0.f;
    for (int k = 0; k < KTOP; ++k) {
      float v = cur;
      int a = lane;
#pragma unroll
      for (int off = 32; off > 0; off >>= 1) {
        float v2 = __shfl_xor(v, off, 64);
        int   a2 = __shfl_xor(a, off, 64);
        if (v2 > v || (v2 == v && a2 < a)) { v = v2; a = a2; }
      }
      float wk = __shfl(p, a, 64) * inv;
      wsum += wk;
      if (lane == 0) { twS[tl][k] = wk; tiS[tl][k] = a; }
      if (lane == a) cur = -1e30f;
    }
    if (lane == 0) twS[tl][KTOP] = wsum;
  }
  __syncthreads();
  const int HV = HH / 4;
  for (int i = 0; i < TT / 4; ++i) {
    const int tl = wv * (TT / 4) + i;
    const size_t tg = t0 + tl;
    const float wsm = twS[tl][KTOP];
    float wk[KTOP];
    const float4* ebp[KTOP];
#pragma unroll
    for (int k = 0; k < KTOP; ++k) {
      wk[k]  = twS[tl][k];
      ebp[k] = reinterpret_cast<const float4*>(eb + (size_t)tiS[tl][k] * HH);
    }
    const float4* fr   = reinterpret_cast<const float4*>(flat + tg * HH);
    float4*       orow = reinterpret_cast<float4*>(out + tg * HH);
#pragma unroll 2
    for (int h = lane; h < HV; h += 64) {
      float4 x = fr[h];
      float4 o;
      o.x = x.x * wsm; o.y = x.y * wsm; o.z = x.z * wsm; o.w = x.w * wsm;
#pragma unroll
      for (int k = 0; k < KTOP; ++k) {
        float4 b = ebp[k][h];
        o.x = fmaf(wk[k], b.x, o.x);
        o.y = fmaf(wk[k], b.y, o.y);
        o.z = fmaf(wk[k], b.z, o.z);
        o.w = fmaf(wk[k], b.w, o.w);
      }
      orow[h] = o;
    }
  }
}

extern "C" void kernel_launch(void* const* d_in, const int* in_sizes, int n_in,
                              void* d_out, int out_size, void* d_ws, size_t ws_size,
                              hipStream_t stream) {
  const float* flat = (const float*)d_in[0];   // hidden_states [4,4096,4096]
  const float* rw   = (const float*)d_in[1];   // router_weight [64,4096]
  const float* rb   = (const float*)d_in[2];   // router_bias [64]
  const float* eb   = (const float*)d_in[3];   // expert_bias [64,4096]
  float* out = (float*)d_out;

  const int T = in_sizes[0] / HH;              // 16384

  if (ws_size >= WS_REQ(T)) {
    char* ws = (char*)d_ws;
    short* whi  = (short*)(ws + WS_WHI);
    short* wlo  = (short*)(ws + WS_WLO);
    float* tw   = (float*)(ws + WS_TW);
    float* tsum = (float*)(ws + WS_TSUM(T));
    int*   tidx = (int*)(ws + WS_TIDX(T));

    prep_split<<<dim3(EE * HH / 8 / 256), dim3(256), 0, stream>>>(rw, whi, wlo);
    router_topk<<<dim3(T / 16), dim3(256), 0, stream>>>(flat, whi, wlo, rb, tw, tsum, tidx);
    combine_stream<<<dim3(T / 8), dim3(256), 0, stream>>>(flat, eb, tw, tsum, tidx, out);
  } else {
    moe_router_combine<<<dim3(T / TT), dim3(NT), 0, stream>>>(flat, rw, rb, eb, out);
  }
}